// Round 8
// baseline (2412.907 us; speedup 1.0000x reference)
//
#include <hip/hip_runtime.h>

// GumbelVQ — fused single main pass with embedding in LDS.
// Outputs (concatenated float32 in d_out):
//   [0 .. 8388607]      quantized  [16,16384,32]
//   [8388608]           commitment_loss (scalar)
//   [8388609 .. 8650752] indices   [16,16384] (stored as float)
//   [8650753]           perplexity (scalar)
//
// ws float layout:
//   [0..255]    avg_probs accumulator
//   [256]       loss accumulator
//   [257..512]  ||e_k||^2
//   [1024 .. 1024+M)  invS per row
//   floats from 1024+M : p (unnormalized numerators) bf16 [M][256]
//
// Round-8 design, from r6/r7 post-mortems:
//  - r6 showed scalar e-loads cap the wave at ~40% duty: s_loads return OUT OF
//    ORDER so only lgkmcnt(0) is usable -> no >1-code pipelining. Fix: stage
//    E (32 KB) + ||e||^2 (1 KB) in LDS once per block; per-code reads become
//    broadcast ds_read_b128 (in-order, compiler pipelines with counted lgkmcnt,
//    zero bank conflicts on uniform addresses).
//  - r7 showed dynamic packs indexing -> scratch (WRITE +144 MB). Restore r3's
//    static pattern: inner 32-code loop fully unrolled, packs[kk>>1] static,
//    p stored as full 64B lines.
//  - keep dot+q fusion (no pass2): q-accum reuses the same e just read.

#define M_ROWS  262144
#define OUT_LOSS 8388608
#define OUT_IDX  8388609
#define OUT_PPL  8650753

__device__ __forceinline__ unsigned int f2bf_u(float f) {
  unsigned int u = __float_as_uint(f);
  u += 0x7fffu + ((u >> 16) & 1u);
  return u >> 16;
}
__device__ __forceinline__ float bf2f(unsigned int lo16) {
  return __uint_as_float(lo16 << 16);
}

__global__ __launch_bounds__(256) void vq_prep(const float* __restrict__ emb,
                                               float* __restrict__ ws) {
  int t = threadIdx.x;
  ws[t] = 0.0f;                 // avg accumulators
  if (t == 0) ws[256] = 0.0f;   // loss accumulator
  const float4* e4 = (const float4*)emb;
  float s = 0.0f;
#pragma unroll
  for (int j = 0; j < 8; ++j) {
    float4 v = e4[t * 8 + j];
    s += v.x * v.x + v.y * v.y + v.z * v.z + v.w * v.w;
  }
  ws[257 + t] = s;
}

// ---- fused main pass: logits, p(bf16)->ws, invS, argmax, loss, quantized ----
// 1024 blocks x 256 thr, thread-per-row; E + ||e||^2 staged in LDS.
__global__ __launch_bounds__(256, 2) void vq_pass1(
    const float* __restrict__ x_in, const float* __restrict__ emb,
    const float* __restrict__ gum, const float* __restrict__ ne,
    float* __restrict__ invS_ws, unsigned short* __restrict__ p_ws,
    float* __restrict__ loss_ws, float* __restrict__ out) {
  __shared__ __align__(16) float e_lds[256 * 32];   // 32 KB
  __shared__ float ne_lds[256];                     // 1 KB

  const int tid  = threadIdx.x;
  const int lane = tid & 63;
  const int row  = blockIdx.x * 256 + tid;

  // stage embedding + norms (coalesced; 8 x float4 per thread)
  {
    const float4* src = (const float4*)emb;
    float4* dst = (float4*)e_lds;
#pragma unroll
    for (int j = 0; j < 8; ++j) dst[j * 256 + tid] = src[j * 256 + tid];
    ne_lds[tid] = ne[tid];
  }

  float xr[32];
  {
    const float4* xv = (const float4*)(x_in + (size_t)row * 32);
#pragma unroll
    for (int j = 0; j < 8; ++j) {
      float4 v = xv[j];
      xr[4*j+0] = v.x; xr[4*j+1] = v.y; xr[4*j+2] = v.z; xr[4*j+3] = v.w;
    }
  }
  __syncthreads();

  float q[32];
#pragma unroll
  for (int d = 0; d < 32; ++d) q[d] = 0.0f;

  const float4* g4  = (const float4*)(gum + (size_t)row * 256);
  const float4* el4 = (const float4*)e_lds;
  uint4* pout = (uint4*)(p_ws + (size_t)row * 256);

  float ssum = 0.0f;
  float tmax = -3.0e38f;
  int   imax = 0;

  for (int kg = 0; kg < 8; ++kg) {          // 8 groups of 32 codes
    unsigned int packs[16];
#pragma unroll
    for (int s = 0; s < 8; ++s) {           // one float4 of gumbel per 4 codes
      const float4 uvv = g4[kg * 8 + s];
#pragma unroll
      for (int j4 = 0; j4 < 4; ++j4) {
        const int kk = s * 4 + j4;          // static under unroll
        const int k  = kg * 32 + kk;
        const float u = (j4 == 0) ? uvv.x : (j4 == 1) ? uvv.y
                      : (j4 == 2) ? uvv.z : uvv.w;
        const float g = -__logf(-__logf(u + 1e-20f) + 1e-20f);

        // e-row from LDS: 8 broadcast ds_read_b128 (in-order -> pipelineable)
        float4 er[8];
#pragma unroll
        for (int jj = 0; jj < 8; ++jj) er[jj] = el4[k * 8 + jj];

        float d0 = 0.f, d1 = 0.f, d2 = 0.f, d3 = 0.f;
#pragma unroll
        for (int jj = 0; jj < 8; ++jj) {
          d0 = fmaf(xr[4*jj+0], er[jj].x, d0);
          d1 = fmaf(xr[4*jj+1], er[jj].y, d1);
          d2 = fmaf(xr[4*jj+2], er[jj].z, d2);
          d3 = fmaf(xr[4*jj+3], er[jj].w, d3);
        }
        const float dot = (d0 + d1) + (d2 + d3);
        const float t = fmaf(2.0f, dot, g) - ne_lds[k];  // ||x||^2 row-const
        const float p = __expf(t);
        ssum += p;
        if (t > tmax) { tmax = t; imax = k; }
        // fused q-accumulation on the same e-row
#pragma unroll
        for (int jj = 0; jj < 8; ++jj) {
          q[4*jj+0] = fmaf(p, er[jj].x, q[4*jj+0]);
          q[4*jj+1] = fmaf(p, er[jj].y, q[4*jj+1]);
          q[4*jj+2] = fmaf(p, er[jj].z, q[4*jj+2]);
          q[4*jj+3] = fmaf(p, er[jj].w, q[4*jj+3]);
        }
        if (kk & 1) packs[kk >> 1] |= f2bf_u(p) << 16;   // static index
        else        packs[kk >> 1]  = f2bf_u(p);
      }
    }
    // one FULL 64B line of p per group: 4 consecutive 16B stores
    const uint4* pd = (const uint4*)packs;
#pragma unroll
    for (int j = 0; j < 4; ++j) pout[kg * 4 + j] = pd[j];
  }

  const float invS = 1.0f / ssum;
  invS_ws[row] = invS;
  out[OUT_IDX + row] = (float)imax;

  // epilogue: quantized + commitment loss (e_hard from LDS)
  {
    const float tr  = 1.0f / 3.0f;     // (1.0-0.5)/(2.0-0.5)
    const float otr = 1.0f - tr;
    const float4* ehv = el4 + imax * 8;
    float4* outq = (float4*)(out + (size_t)row * 32);
    float cl = 0.0f;
#pragma unroll
    for (int j = 0; j < 8; ++j) {
      float4 e = ehv[j];
      float4 o;
      float dx;
      o.x = fmaf(tr, q[4*j+0] * invS, otr * e.x);
      o.y = fmaf(tr, q[4*j+1] * invS, otr * e.y);
      o.z = fmaf(tr, q[4*j+2] * invS, otr * e.z);
      o.w = fmaf(tr, q[4*j+3] * invS, otr * e.w);
      outq[j] = o;
      dx = e.x - xr[4*j+0]; cl = fmaf(dx, dx, cl);
      dx = e.y - xr[4*j+1]; cl = fmaf(dx, dx, cl);
      dx = e.z - xr[4*j+2]; cl = fmaf(dx, dx, cl);
      dx = e.w - xr[4*j+3]; cl = fmaf(dx, dx, cl);
    }
#pragma unroll
    for (int off = 32; off > 0; off >>= 1) cl += __shfl_down(cl, off);
    if (lane == 0) atomicAdd(loss_ws, cl);
  }
}

// ---- avg_probs column sums (coalesced, 8192 waves) --------------------------
__global__ __launch_bounds__(256) void vq_avg(
    const unsigned short* __restrict__ p_ws, const float* __restrict__ invS_ws,
    float* __restrict__ avg_ws) {
  __shared__ float sh[256];
  const int tid = threadIdx.x, lane = tid & 63, w = tid >> 6;
  sh[tid] = 0.0f;
  __syncthreads();
  const int base = (blockIdx.x * 4 + w) * 32;   // 8192 waves, 32 rows each
  const float iv = invS_ws[base + (lane & 31)];
  float a0 = 0.f, a1 = 0.f, a2 = 0.f, a3 = 0.f;
#pragma unroll 4
  for (int r = 0; r < 32; ++r) {
    const float s = __shfl(iv, r);
    const unsigned short* pr = p_ws + (size_t)(base + r) * 256;
    a0 = fmaf(bf2f(pr[  0 + lane]), s, a0);
    a1 = fmaf(bf2f(pr[ 64 + lane]), s, a1);
    a2 = fmaf(bf2f(pr[128 + lane]), s, a2);
    a3 = fmaf(bf2f(pr[192 + lane]), s, a3);
  }
  atomicAdd(&sh[  0 + lane], a0);
  atomicAdd(&sh[ 64 + lane], a1);
  atomicAdd(&sh[128 + lane], a2);
  atomicAdd(&sh[192 + lane], a3);
  __syncthreads();
  atomicAdd(&avg_ws[tid], sh[tid]);
}

__global__ __launch_bounds__(256) void vq_fin(const float* __restrict__ ws,
                                              float* __restrict__ out) {
  __shared__ float red[256];
  int t = threadIdx.x;
  float avg = ws[t] * (1.0f / 262144.0f);
  red[t] = -avg * __logf(avg + 1e-10f);
  __syncthreads();
  for (int s = 128; s > 0; s >>= 1) {
    if (t < s) red[t] += red[t + s];
    __syncthreads();
  }
  if (t == 0) {
    out[OUT_PPL]  = __expf(red[0]);
    out[OUT_LOSS] = ws[256] * (1.0f / 8388608.0f);
  }
}

// ---- fallback (round-1 monolithic, if ws too small) -------------------------
__global__ __launch_bounds__(256, 1) void vq_main(
    const float* __restrict__ x_in, const float* __restrict__ emb,
    const float* __restrict__ gum, const float* __restrict__ ne,
    float* __restrict__ avg_ws, float* __restrict__ loss_ws,
    float* __restrict__ out) {
  extern __shared__ unsigned char dynsmem[];
  unsigned short* p_lds = (unsigned short*)dynsmem;

  const int tid  = threadIdx.x;
  const int lane = tid & 63;
  const int w    = tid >> 6;
  const int row  = blockIdx.x * 256 + tid;
  unsigned short* my_p = p_lds + (size_t)(w * 64 + lane) * 258;

  float xr[32];
  {
    const float4* xv = (const float4*)(x_in + (size_t)row * 32);
#pragma unroll
    for (int j = 0; j < 8; ++j) {
      float4 v = xv[j];
      xr[4*j+0] = v.x; xr[4*j+1] = v.y; xr[4*j+2] = v.z; xr[4*j+3] = v.w;
    }
  }
  float q[32];
#pragma unroll
  for (int d = 0; d < 32; ++d) q[d] = 0.0f;

  float ssum = 0.0f;
  float tmax = -3.0e38f;
  int   imax = 0;

  const float4* g4 = (const float4*)(gum + (size_t)row * 256);
  const float4* e4 = (const float4*)emb;

  for (int kg = 0; kg < 8; ++kg) {
    float uv[32];
#pragma unroll
    for (int j = 0; j < 8; ++j) {
      float4 v = g4[kg * 8 + j];
      uv[4*j+0] = v.x; uv[4*j+1] = v.y; uv[4*j+2] = v.z; uv[4*j+3] = v.w;
    }
#pragma unroll
    for (int kk = 0; kk < 32; ++kk) {
      const int k = kg * 32 + kk;
      float er[32];
#pragma unroll
      for (int j = 0; j < 8; ++j) {
        float4 v = e4[k * 8 + j];
        er[4*j+0] = v.x; er[4*j+1] = v.y; er[4*j+2] = v.z; er[4*j+3] = v.w;
      }
      float d0 = 0.f, d1 = 0.f, d2 = 0.f, d3 = 0.f;
#pragma unroll
      for (int d = 0; d < 32; d += 4) {
        d0 = fmaf(xr[d+0], er[d+0], d0);
        d1 = fmaf(xr[d+1], er[d+1], d1);
        d2 = fmaf(xr[d+2], er[d+2], d2);
        d3 = fmaf(xr[d+3], er[d+3], d3);
      }
      const float dot = (d0 + d1) + (d2 + d3);
      const float inner = -__logf(uv[kk] + 1e-20f);
      const float g = -__logf(inner + 1e-20f);
      const float t = fmaf(2.0f, dot, g) - ne[k];
      const float p = __expf(t);
      ssum += p;
      if (t > tmax) { tmax = t; imax = k; }
#pragma unroll
      for (int d = 0; d < 32; ++d) q[d] = fmaf(p, er[d], q[d]);
      my_p[k] = (unsigned short)f2bf_u(p);
    }
  }

  const float invS = 1.0f / ssum;
  {
    const float tr  = 1.0f / 3.0f;
    const float otr = 1.0f - tr;
    const float4* ehv = (const float4*)(emb + (size_t)imax * 32);
    float4* outq = (float4*)(out + (size_t)row * 32);
    float cl = 0.0f;
#pragma unroll
    for (int j = 0; j < 8; ++j) {
      float4 e = ehv[j];
      float4 o;
      float qs, dx;
      qs = q[4*j+0]*invS; o.x = tr*qs + otr*e.x; dx = e.x - xr[4*j+0]; cl = fmaf(dx,dx,cl);
      qs = q[4*j+1]*invS; o.y = tr*qs + otr*e.y; dx = e.y - xr[4*j+1]; cl = fmaf(dx,dx,cl);
      qs = q[4*j+2]*invS; o.z = tr*qs + otr*e.z; dx = e.z - xr[4*j+2]; cl = fmaf(dx,dx,cl);
      qs = q[4*j+3]*invS; o.w = tr*qs + otr*e.w; dx = e.w - xr[4*j+3]; cl = fmaf(dx,dx,cl);
      outq[j] = o;
    }
    out[OUT_IDX + row] = (float)imax;
#pragma unroll
    for (int off = 32; off > 0; off >>= 1) cl += __shfl_down(cl, off);
    if (lane == 0) atomicAdd(loss_ws, cl);
  }

  __syncthreads();

  float a0 = 0.f, a1 = 0.f, a2 = 0.f, a3 = 0.f;
  for (int r = 0; r < 64; ++r) {
    const float invS_r = __shfl(invS, r);
    const unsigned short* rp = p_lds + (size_t)(w * 64 + r) * 258;
    a0 = fmaf(bf2f(rp[  0 + lane]), invS_r, a0);
    a1 = fmaf(bf2f(rp[ 64 + lane]), invS_r, a1);
    a2 = fmaf(bf2f(rp[128 + lane]), invS_r, a2);
    a3 = fmaf(bf2f(rp[192 + lane]), invS_r, a3);
  }
  atomicAdd(&avg_ws[  0 + lane], a0);
  atomicAdd(&avg_ws[ 64 + lane], a1);
  atomicAdd(&avg_ws[128 + lane], a2);
  atomicAdd(&avg_ws[192 + lane], a3);
}

extern "C" void kernel_launch(void* const* d_in, const int* in_sizes, int n_in,
                              void* d_out, int out_size, void* d_ws, size_t ws_size,
                              hipStream_t stream) {
  const float* x   = (const float*)d_in[0];
  const float* emb = (const float*)d_in[1];
  const float* gum = (const float*)d_in[2];
  float* out = (float*)d_out;
  float* ws  = (float*)d_ws;

  (void)in_sizes; (void)n_in; (void)out_size;

  vq_prep<<<1, 256, 0, stream>>>(emb, ws);

  const size_t need = (size_t)(1024 + M_ROWS) * 4 + (size_t)M_ROWS * 256 * 2;
  if (ws_size >= need) {
    float* invS = ws + 1024;
    unsigned short* p = (unsigned short*)(ws + 1024 + M_ROWS);
    vq_pass1<<<1024, 256, 0, stream>>>(x, emb, gum, ws + 257, invS, p, ws + 256, out);
    vq_avg<<<2048, 256, 0, stream>>>(p, invS, ws);
  } else {
    hipFuncSetAttribute((const void*)vq_main,
                        hipFuncAttributeMaxDynamicSharedMemorySize, 132128);
    vq_main<<<1024, 256, 132128, stream>>>(x, emb, gum, ws + 257, ws, ws + 256, out);
  }
  vq_fin<<<1, 256, 0, stream>>>(ws, out);
}

// Round 9
// 460.492 us; speedup vs baseline: 5.2398x; 5.2398x over previous
//
#include <hip/hip_runtime.h>

// GumbelVQ — lane=code GEMM-phase pass1 + proven r3 pass2.
// Outputs (concatenated float32 in d_out):
//   [0 .. 8388607]      quantized  [16,16384,32]
//   [8388608]           commitment_loss (scalar)
//   [8388609 .. 8650752] indices   [16,16384] (stored as float)
//   [8650753]           perplexity (scalar)
//
// ws float layout:
//   [0..255]    avg_probs accumulator
//   [256]       loss accumulator
//   [257..512]  ||e_k||^2
//   [1024 .. 1024+M)  invS per row
//   floats from 1024+M : p (unnormalized numerators) bf16 [M][256]
//
// Round-9 design. Root cause across r5-r8: every structure reloaded E per
// (row,code) — scalar s_loads drain out-of-order (r6), per-lane global floods
// VMEM (r5), LDS-reread + reg-held rows spills (r8: 8.4 GB scratch = the
// whole 2.3ms). Fix: LANE=CODE. Thread t keeps e[t][0..31] in 32 VGPRs,
// loaded ONCE. Per 32-row tile:
//   phase A (lane=code): dot via UNIFORM x_lds reads (~1cyc broadcast, r8
//     datum); gumbel now coalesced (gum[r][tid]); logits -> t_lds[code][row]
//     (stride 33 -> (tid+r)%32 banks, conflict-free).
//   phase B (thread = row + 8 code-slices): exp/sum/argmax/bf16-pack from
//     t_lds ((j+row)%32 banks, 2 lanes/bank = free), 64B p-stores, LDS
//     combine across slices, loss for 32 rows.
// q = p-hat @ E stays in r3's separate pass2 (thread-per-row, wave-uniform
// scalar e-loads, latency covered by TLP — measured ~35us).

#define M_ROWS  262144
#define OUT_LOSS 8388608
#define OUT_IDX  8388609
#define OUT_PPL  8650753

__device__ __forceinline__ unsigned int f2bf_u(float f) {
  unsigned int u = __float_as_uint(f);
  u += 0x7fffu + ((u >> 16) & 1u);
  return u >> 16;
}
__device__ __forceinline__ float bf2f(unsigned int lo16) {
  return __uint_as_float(lo16 << 16);
}

__global__ __launch_bounds__(256) void vq_prep(const float* __restrict__ emb,
                                               float* __restrict__ ws) {
  int t = threadIdx.x;
  ws[t] = 0.0f;                 // avg accumulators
  if (t == 0) ws[256] = 0.0f;   // loss accumulator
  const float4* e4 = (const float4*)emb;
  float s = 0.0f;
#pragma unroll
  for (int j = 0; j < 8; ++j) {
    float4 v = e4[t * 8 + j];
    s += v.x * v.x + v.y * v.y + v.z * v.z + v.w * v.w;
  }
  ws[257 + t] = s;
}

// ---- pass 1 (lane=code): logits, p(bf16), invS, argmax, loss ----------------
// 1024 blocks x 256 thr; block owns 256 rows in 8 tiles of 32.
__global__ __launch_bounds__(256, 2) void vq_pass1(
    const float* __restrict__ x_in, const float* __restrict__ emb,
    const float* __restrict__ gum, const float* __restrict__ ne,
    float* __restrict__ invS_ws, unsigned short* __restrict__ p_ws,
    float* __restrict__ loss_ws, float* __restrict__ out) {
  __shared__ __align__(16) float x_lds[32 * 36];   // stride 36: 16B-aligned rows
  __shared__ float t_lds[256 * 33];                // [code][row], stride 33
  __shared__ float red_sum[32 * 9];
  __shared__ float red_max[32 * 9];
  __shared__ int   red_idx[32 * 9];

  const int tid = threadIdx.x;

  // embedding row for code=tid, resident in VGPRs for the whole kernel
  float er[32];
  {
    const float4* e4 = (const float4*)(emb + tid * 32);
#pragma unroll
    for (int j = 0; j < 8; ++j) {
      float4 v = e4[j];
      er[4*j+0] = v.x; er[4*j+1] = v.y; er[4*j+2] = v.z; er[4*j+3] = v.w;
    }
  }
  const float ne_t = ne[tid];
  const int row_blk = blockIdx.x * 256;

  for (int tt = 0; tt < 8; ++tt) {
    const int r0 = row_blk + tt * 32;

    // stage 32 rows of x (one float4 per thread, coalesced)
    {
      const float4 v = ((const float4*)x_in)[(size_t)r0 * 8 + tid];
      *((float4*)&x_lds[(tid >> 3) * 36 + (tid & 7) * 4]) = v;
    }
    __syncthreads();

    // ---- phase A: logits for 32 rows x (code = tid) ----
    for (int r = 0; r < 32; ++r) {
      const float* xr = &x_lds[r * 36];
      float d0 = 0.f, d1 = 0.f, d2 = 0.f, d3 = 0.f;
#pragma unroll
      for (int j = 0; j < 8; ++j) {
        const float4 xv = ((const float4*)xr)[j];   // uniform broadcast read
        d0 = fmaf(xv.x, er[4*j+0], d0);
        d1 = fmaf(xv.y, er[4*j+1], d1);
        d2 = fmaf(xv.z, er[4*j+2], d2);
        d3 = fmaf(xv.w, er[4*j+3], d3);
      }
      const float dot = (d0 + d1) + (d2 + d3);
      const float u = gum[(size_t)(r0 + r) * 256 + tid];   // coalesced
      const float g = -__logf(-__logf(u + 1e-20f) + 1e-20f);
      t_lds[tid * 33 + r] = fmaf(2.0f, dot, g) - ne_t;     // ||x||^2 row-const
    }
    __syncthreads();

    // ---- phase B: softmax stats + p for row=tid&31, codes (tid>>5)*32.. ----
    const int lrow = tid & 31;
    const int cs   = tid >> 5;
    {
      float ssum = 0.0f, tmax = -3.0e38f;
      int   kmax = 0;
      unsigned int packs[16];
#pragma unroll
      for (int j = 0; j < 32; ++j) {
        const int k = cs * 32 + j;
        const float tv = t_lds[k * 33 + lrow];
        const float p = __expf(tv);
        ssum += p;
        if (tv > tmax) { tmax = tv; kmax = k; }
        if (j & 1) packs[j >> 1] |= f2bf_u(p) << 16;   // static index
        else       packs[j >> 1]  = f2bf_u(p);
      }
      uint4* pout = (uint4*)(p_ws + (size_t)(r0 + lrow) * 256 + cs * 32);
      const uint4* pd = (const uint4*)packs;
#pragma unroll
      for (int j = 0; j < 4; ++j) pout[j] = pd[j];     // full 64B line
      red_sum[lrow * 9 + cs] = ssum;
      red_max[lrow * 9 + cs] = tmax;
      red_idx[lrow * 9 + cs] = kmax;
    }
    __syncthreads();

    // ---- combine slices, write invS/idx, commitment loss (1 thr/row) ----
    if (tid < 32) {
      float ssum = 0.0f, tmax = -3.0e38f;
      int   kmax = 0;
#pragma unroll
      for (int c = 0; c < 8; ++c) {        // ascending c keeps first-index ties
        ssum += red_sum[tid * 9 + c];
        const float m = red_max[tid * 9 + c];
        if (m > tmax) { tmax = m; kmax = red_idx[tid * 9 + c]; }
      }
      const int rg = r0 + tid;
      invS_ws[rg] = 1.0f / ssum;
      out[OUT_IDX + rg] = (float)kmax;

      const float4* eh = (const float4*)(emb + (size_t)kmax * 32);  // L1-hot
      const float* xrr = &x_lds[tid * 36];
      float cl = 0.0f;
#pragma unroll
      for (int j = 0; j < 8; ++j) {
        const float4 e  = eh[j];
        const float4 xv = ((const float4*)xrr)[j];
        float dx;
        dx = e.x - xv.x; cl = fmaf(dx, dx, cl);
        dx = e.y - xv.y; cl = fmaf(dx, dx, cl);
        dx = e.z - xv.z; cl = fmaf(dx, dx, cl);
        dx = e.w - xv.w; cl = fmaf(dx, dx, cl);
      }
#pragma unroll
      for (int off = 16; off > 0; off >>= 1) cl += __shfl_down(cl, off, 32);
      if (tid == 0) atomicAdd(loss_ws, cl);
    }
    __syncthreads();
  }
}

// ---- pass 2 (r3-proven): quantized = tr*(p-hat @ E) + (1-tr)*e_hard ---------
__global__ __launch_bounds__(256, 4) void vq_pass2(
    const float* __restrict__ emb, const unsigned short* __restrict__ p_ws,
    const float* __restrict__ invS_ws, float* __restrict__ out) {
  const int row = blockIdx.x * 256 + threadIdx.x;
  const float invS = invS_ws[row];
  const int imax = (int)out[OUT_IDX + row];
  const uint4* pv = (const uint4*)(p_ws + (size_t)row * 256);
  const float4* e4 = (const float4*)emb;

  float q[32];
#pragma unroll
  for (int d = 0; d < 32; ++d) q[d] = 0.0f;

  for (int kg = 0; kg < 8; ++kg) {
    unsigned int w_[16];
#pragma unroll
    for (int j = 0; j < 4; ++j) {
      const uint4 v = pv[kg * 4 + j];
      w_[4*j+0] = v.x; w_[4*j+1] = v.y; w_[4*j+2] = v.z; w_[4*j+3] = v.w;
    }
#pragma unroll
    for (int i = 0; i < 16; ++i) {
      const int k0 = kg * 32 + 2 * i;
      const float p0 = bf2f(w_[i] & 0xffffu);
      const float p1 = bf2f(w_[i] >> 16);
#pragma unroll
      for (int jj = 0; jj < 8; ++jj) {
        const float4 e0 = e4[k0 * 8 + jj];        // wave-uniform -> s_load
        const float4 e1 = e4[(k0 + 1) * 8 + jj];
        q[4*jj+0] = fmaf(p0, e0.x, fmaf(p1, e1.x, q[4*jj+0]));
        q[4*jj+1] = fmaf(p0, e0.y, fmaf(p1, e1.y, q[4*jj+1]));
        q[4*jj+2] = fmaf(p0, e0.z, fmaf(p1, e1.z, q[4*jj+2]));
        q[4*jj+3] = fmaf(p0, e0.w, fmaf(p1, e1.w, q[4*jj+3]));
      }
    }
  }

  const float tr  = 1.0f / 3.0f;     // (1.0-0.5)/(2.0-0.5)
  const float otr = 1.0f - tr;
  const float4* ehv = (const float4*)(emb + (size_t)imax * 32);
  float4* outq = (float4*)(out + (size_t)row * 32);
#pragma unroll
  for (int j = 0; j < 8; ++j) {
    float4 e = ehv[j];
    float4 o;
    o.x = fmaf(tr, q[4*j+0] * invS, otr * e.x);
    o.y = fmaf(tr, q[4*j+1] * invS, otr * e.y);
    o.z = fmaf(tr, q[4*j+2] * invS, otr * e.z);
    o.w = fmaf(tr, q[4*j+3] * invS, otr * e.w);
    outq[j] = o;
  }
}

// ---- avg_probs column sums (coalesced, 8192 waves) --------------------------
__global__ __launch_bounds__(256) void vq_avg(
    const unsigned short* __restrict__ p_ws, const float* __restrict__ invS_ws,
    float* __restrict__ avg_ws) {
  __shared__ float sh[256];
  const int tid = threadIdx.x, lane = tid & 63, w = tid >> 6;
  sh[tid] = 0.0f;
  __syncthreads();
  const int base = (blockIdx.x * 4 + w) * 32;   // 8192 waves, 32 rows each
  const float iv = invS_ws[base + (lane & 31)];
  float a0 = 0.f, a1 = 0.f, a2 = 0.f, a3 = 0.f;
#pragma unroll 4
  for (int r = 0; r < 32; ++r) {
    const float s = __shfl(iv, r);
    const unsigned short* pr = p_ws + (size_t)(base + r) * 256;
    a0 = fmaf(bf2f(pr[  0 + lane]), s, a0);
    a1 = fmaf(bf2f(pr[ 64 + lane]), s, a1);
    a2 = fmaf(bf2f(pr[128 + lane]), s, a2);
    a3 = fmaf(bf2f(pr[192 + lane]), s, a3);
  }
  atomicAdd(&sh[  0 + lane], a0);
  atomicAdd(&sh[ 64 + lane], a1);
  atomicAdd(&sh[128 + lane], a2);
  atomicAdd(&sh[192 + lane], a3);
  __syncthreads();
  atomicAdd(&avg_ws[tid], sh[tid]);
}

__global__ __launch_bounds__(256) void vq_fin(const float* __restrict__ ws,
                                              float* __restrict__ out) {
  __shared__ float red[256];
  int t = threadIdx.x;
  float avg = ws[t] * (1.0f / 262144.0f);
  red[t] = -avg * __logf(avg + 1e-10f);
  __syncthreads();
  for (int s = 128; s > 0; s >>= 1) {
    if (t < s) red[t] += red[t + s];
    __syncthreads();
  }
  if (t == 0) {
    out[OUT_PPL]  = __expf(red[0]);
    out[OUT_LOSS] = ws[256] * (1.0f / 8388608.0f);
  }
}

// ---- fallback (round-1 monolithic, if ws too small) -------------------------
__global__ __launch_bounds__(256, 1) void vq_main(
    const float* __restrict__ x_in, const float* __restrict__ emb,
    const float* __restrict__ gum, const float* __restrict__ ne,
    float* __restrict__ avg_ws, float* __restrict__ loss_ws,
    float* __restrict__ out) {
  extern __shared__ unsigned char dynsmem[];
  unsigned short* p_lds = (unsigned short*)dynsmem;

  const int tid  = threadIdx.x;
  const int lane = tid & 63;
  const int w    = tid >> 6;
  const int row  = blockIdx.x * 256 + tid;
  unsigned short* my_p = p_lds + (size_t)(w * 64 + lane) * 258;

  float xr[32];
  {
    const float4* xv = (const float4*)(x_in + (size_t)row * 32);
#pragma unroll
    for (int j = 0; j < 8; ++j) {
      float4 v = xv[j];
      xr[4*j+0] = v.x; xr[4*j+1] = v.y; xr[4*j+2] = v.z; xr[4*j+3] = v.w;
    }
  }
  float q[32];
#pragma unroll
  for (int d = 0; d < 32; ++d) q[d] = 0.0f;

  float ssum = 0.0f;
  float tmax = -3.0e38f;
  int   imax = 0;

  const float4* g4 = (const float4*)(gum + (size_t)row * 256);
  const float4* e4 = (const float4*)emb;

  for (int kg = 0; kg < 8; ++kg) {
    float uv[32];
#pragma unroll
    for (int j = 0; j < 8; ++j) {
      float4 v = g4[kg * 8 + j];
      uv[4*j+0] = v.x; uv[4*j+1] = v.y; uv[4*j+2] = v.z; uv[4*j+3] = v.w;
    }
#pragma unroll
    for (int kk = 0; kk < 32; ++kk) {
      const int k = kg * 32 + kk;
      float er[32];
#pragma unroll
      for (int j = 0; j < 8; ++j) {
        float4 v = e4[k * 8 + j];
        er[4*j+0] = v.x; er[4*j+1] = v.y; er[4*j+2] = v.z; er[4*j+3] = v.w;
      }
      float d0 = 0.f, d1 = 0.f, d2 = 0.f, d3 = 0.f;
#pragma unroll
      for (int d = 0; d < 32; d += 4) {
        d0 = fmaf(xr[d+0], er[d+0], d0);
        d1 = fmaf(xr[d+1], er[d+1], d1);
        d2 = fmaf(xr[d+2], er[d+2], d2);
        d3 = fmaf(xr[d+3], er[d+3], d3);
      }
      const float dot = (d0 + d1) + (d2 + d3);
      const float inner = -__logf(uv[kk] + 1e-20f);
      const float g = -__logf(inner + 1e-20f);
      const float t = fmaf(2.0f, dot, g) - ne[k];
      const float p = __expf(t);
      ssum += p;
      if (t > tmax) { tmax = t; imax = k; }
#pragma unroll
      for (int d = 0; d < 32; ++d) q[d] = fmaf(p, er[d], q[d]);
      my_p[k] = (unsigned short)f2bf_u(p);
    }
  }

  const float invS = 1.0f / ssum;
  {
    const float tr  = 1.0f / 3.0f;
    const float otr = 1.0f - tr;
    const float4* ehv = (const float4*)(emb + (size_t)imax * 32);
    float4* outq = (float4*)(out + (size_t)row * 32);
    float cl = 0.0f;
#pragma unroll
    for (int j = 0; j < 8; ++j) {
      float4 e = ehv[j];
      float4 o;
      float qs, dx;
      qs = q[4*j+0]*invS; o.x = tr*qs + otr*e.x; dx = e.x - xr[4*j+0]; cl = fmaf(dx,dx,cl);
      qs = q[4*j+1]*invS; o.y = tr*qs + otr*e.y; dx = e.y - xr[4*j+1]; cl = fmaf(dx,dx,cl);
      qs = q[4*j+2]*invS; o.z = tr*qs + otr*e.z; dx = e.z - xr[4*j+2]; cl = fmaf(dx,dx,cl);
      qs = q[4*j+3]*invS; o.w = tr*qs + otr*e.w; dx = e.w - xr[4*j+3]; cl = fmaf(dx,dx,cl);
      outq[j] = o;
    }
    out[OUT_IDX + row] = (float)imax;
#pragma unroll
    for (int off = 32; off > 0; off >>= 1) cl += __shfl_down(cl, off);
    if (lane == 0) atomicAdd(loss_ws, cl);
  }

  __syncthreads();

  float a0 = 0.f, a1 = 0.f, a2 = 0.f, a3 = 0.f;
  for (int r = 0; r < 64; ++r) {
    const float invS_r = __shfl(invS, r);
    const unsigned short* rp = p_lds + (size_t)(w * 64 + r) * 258;
    a0 = fmaf(bf2f(rp[  0 + lane]), invS_r, a0);
    a1 = fmaf(bf2f(rp[ 64 + lane]), invS_r, a1);
    a2 = fmaf(bf2f(rp[128 + lane]), invS_r, a2);
    a3 = fmaf(bf2f(rp[192 + lane]), invS_r, a3);
  }
  atomicAdd(&avg_ws[  0 + lane], a0);
  atomicAdd(&avg_ws[ 64 + lane], a1);
  atomicAdd(&avg_ws[128 + lane], a2);
  atomicAdd(&avg_ws[192 + lane], a3);
}

extern "C" void kernel_launch(void* const* d_in, const int* in_sizes, int n_in,
                              void* d_out, int out_size, void* d_ws, size_t ws_size,
                              hipStream_t stream) {
  const float* x   = (const float*)d_in[0];
  const float* emb = (const float*)d_in[1];
  const float* gum = (const float*)d_in[2];
  float* out = (float*)d_out;
  float* ws  = (float*)d_ws;

  (void)in_sizes; (void)n_in; (void)out_size;

  vq_prep<<<1, 256, 0, stream>>>(emb, ws);

  const size_t need = (size_t)(1024 + M_ROWS) * 4 + (size_t)M_ROWS * 256 * 2;
  if (ws_size >= need) {
    float* invS = ws + 1024;
    unsigned short* p = (unsigned short*)(ws + 1024 + M_ROWS);
    vq_pass1<<<1024, 256, 0, stream>>>(x, emb, gum, ws + 257, invS, p, ws + 256, out);
    vq_pass2<<<1024, 256, 0, stream>>>(emb, p, invS, out);
    vq_avg<<<2048, 256, 0, stream>>>(p, invS, ws);
  } else {
    hipFuncSetAttribute((const void*)vq_main,
                        hipFuncAttributeMaxDynamicSharedMemorySize, 132128);
    vq_main<<<1024, 256, 132128, stream>>>(x, emb, gum, ws + 257, ws, ws + 256, out);
  }
  vq_fin<<<1, 256, 0, stream>>>(ws, out);
}

// Round 10
// 343.483 us; speedup vs baseline: 7.0248x; 1.3407x over previous
//
#include <hip/hip_runtime.h>

// GumbelVQ — lane=code pass1 (16-row tiles, LDS-staged gumbel) + r3 pass2.
// Outputs (concatenated float32 in d_out):
//   [0 .. 8388607]      quantized  [16,16384,32]
//   [8388608]           commitment_loss (scalar)
//   [8388609 .. 8650752] indices   [16,16384] (stored as float)
//   [8650753]           perplexity (scalar)
//
// ws float layout:
//   [0..255]    avg_probs accumulator
//   [256]       loss accumulator
//   [257..512]  ||e_k||^2
//   [1024 .. 1024+M)  invS per row
//   floats from 1024+M : p (unnormalized numerators) bf16 [M][256]
//
// Round-10 fixes vs round-9 (362us pass1, VALU 41%, Occ 25%):
//  - gumbel was read as ONE blocking 4B load per r-iteration (256 exposed
//    ~600cy HBM round-trips per thread). Now the 16x256 gumbel tile is bulk-
//    staged to LDS with 4 coalesced float4 loads/thread (latency paid once
//    per tile); phase A reads it at 2-lanes/bank (free).
//  - 32-row -> 16-row tiles: LDS 41.9K -> 39.4K total but per-phase arrays
//    halve -> 4 blocks/CU co-resident (was 2): doubles latency-hiding waves.
//  - phase A unroll 2 for ILP; loss accumulated in a register (1 atomic/blk).

#define M_ROWS  262144
#define OUT_LOSS 8388608
#define OUT_IDX  8388609
#define OUT_PPL  8650753

__device__ __forceinline__ unsigned int f2bf_u(float f) {
  unsigned int u = __float_as_uint(f);
  u += 0x7fffu + ((u >> 16) & 1u);
  return u >> 16;
}
__device__ __forceinline__ float bf2f(unsigned int lo16) {
  return __uint_as_float(lo16 << 16);
}

__global__ __launch_bounds__(256) void vq_prep(const float* __restrict__ emb,
                                               float* __restrict__ ws) {
  int t = threadIdx.x;
  ws[t] = 0.0f;                 // avg accumulators
  if (t == 0) ws[256] = 0.0f;   // loss accumulator
  const float4* e4 = (const float4*)emb;
  float s = 0.0f;
#pragma unroll
  for (int j = 0; j < 8; ++j) {
    float4 v = e4[t * 8 + j];
    s += v.x * v.x + v.y * v.y + v.z * v.z + v.w * v.w;
  }
  ws[257 + t] = s;
}

// ---- pass 1 (lane=code): logits, p(bf16), invS, argmax, loss ----------------
// 1024 blocks x 256 thr; block owns 256 rows in 16 tiles of 16.
__global__ __launch_bounds__(256, 4) void vq_pass1(
    const float* __restrict__ x_in, const float* __restrict__ emb,
    const float* __restrict__ gum, const float* __restrict__ ne,
    float* __restrict__ invS_ws, unsigned short* __restrict__ p_ws,
    float* __restrict__ loss_ws, float* __restrict__ out) {
  __shared__ __align__(16) float x_lds[16 * 36];    // 2304 B (16B-aligned rows)
  __shared__ __align__(16) float g_lds[16 * 256];   // 16384 B gumbel tile
  __shared__ float t_lds[256 * 17];                 // 17408 B [code][row]
  __shared__ float red_sum[16 * 17];                // 1088 B
  __shared__ float red_max[16 * 17];
  __shared__ int   red_idx[16 * 17];

  const int tid = threadIdx.x;

  // embedding row for code=tid, resident in VGPRs for the whole kernel
  float er[32];
  {
    const float4* e4 = (const float4*)(emb + tid * 32);
#pragma unroll
    for (int j = 0; j < 8; ++j) {
      float4 v = e4[j];
      er[4*j+0] = v.x; er[4*j+1] = v.y; er[4*j+2] = v.z; er[4*j+3] = v.w;
    }
  }
  const float ne_t = ne[tid];
  const int row_blk = blockIdx.x * 256;
  float cl_acc = 0.0f;

  for (int tt = 0; tt < 16; ++tt) {
    const int r0 = row_blk + tt * 16;

    // bulk-stage gumbel tile: 4 coalesced float4 loads per thread, all in
    // flight together (one latency, not 16 per thread).
    {
      const float4* gg = (const float4*)gum + (size_t)r0 * 64;
      float4* gd = (float4*)g_lds;
#pragma unroll
      for (int i = 0; i < 4; ++i) gd[i * 256 + tid] = gg[i * 256 + tid];
      if (tid < 128)   // 16 rows of x (one float4 per thread)
        *((float4*)&x_lds[(tid >> 3) * 36 + (tid & 7) * 4]) =
            ((const float4*)x_in)[(size_t)r0 * 8 + tid];
    }
    __syncthreads();

    // ---- phase A: logits for 16 rows x (code = tid) ----
#pragma unroll 2
    for (int r = 0; r < 16; ++r) {
      const float* xr = &x_lds[r * 36];
      float d0 = 0.f, d1 = 0.f, d2 = 0.f, d3 = 0.f;
#pragma unroll
      for (int j = 0; j < 8; ++j) {
        const float4 xv = ((const float4*)xr)[j];   // uniform broadcast read
        d0 = fmaf(xv.x, er[4*j+0], d0);
        d1 = fmaf(xv.y, er[4*j+1], d1);
        d2 = fmaf(xv.z, er[4*j+2], d2);
        d3 = fmaf(xv.w, er[4*j+3], d3);
      }
      const float dot = (d0 + d1) + (d2 + d3);
      const float u = g_lds[r * 256 + tid];              // 2 lanes/bank: free
      const float g = -__logf(-__logf(u + 1e-20f) + 1e-20f);
      t_lds[tid * 17 + r] = fmaf(2.0f, dot, g) - ne_t;   // ||x||^2 row-const
    }
    __syncthreads();

    // ---- phase B: row = tid&15, codes (tid>>4)*16 .. +16 ----
    const int lrow = tid & 15;
    const int cs   = tid >> 4;
    {
      float ssum = 0.0f, tmax = -3.0e38f;
      int   kmax = 0;
      unsigned int packs[8];
#pragma unroll
      for (int j = 0; j < 16; ++j) {
        const int k = cs * 16 + j;
        const float tv = t_lds[k * 17 + lrow];   // (16cs+lrow+17j)%32: 2/bank
        const float p = __expf(tv);
        ssum += p;
        if (tv > tmax) { tmax = tv; kmax = k; }
        if (j & 1) packs[j >> 1] |= f2bf_u(p) << 16;   // static index
        else       packs[j >> 1]  = f2bf_u(p);
      }
      uint4* pout = (uint4*)(p_ws + (size_t)(r0 + lrow) * 256 + cs * 16);
      const uint4* pd = (const uint4*)packs;
      pout[0] = pd[0]; pout[1] = pd[1];          // 32B per thread, coalesced
      red_sum[lrow * 17 + cs] = ssum;
      red_max[lrow * 17 + cs] = tmax;
      red_idx[lrow * 17 + cs] = kmax;
    }
    __syncthreads();

    // ---- combine slices, write invS/idx, commitment loss (1 thr/row) ----
    if (tid < 16) {
      float ssum = 0.0f, tmax = -3.0e38f;
      int   kmax = 0;
#pragma unroll
      for (int c = 0; c < 16; ++c) {       // ascending c keeps first-index ties
        ssum += red_sum[tid * 17 + c];
        const float m = red_max[tid * 17 + c];
        if (m > tmax) { tmax = m; kmax = red_idx[tid * 17 + c]; }
      }
      const int rg = r0 + tid;
      invS_ws[rg] = 1.0f / ssum;
      out[OUT_IDX + rg] = (float)kmax;

      const float4* eh = (const float4*)(emb + (size_t)kmax * 32);  // L1-hot
      const float* xrr = &x_lds[tid * 36];
      float cl = 0.0f;
#pragma unroll
      for (int j = 0; j < 8; ++j) {
        const float4 e  = eh[j];
        const float4 xv = ((const float4*)xrr)[j];
        float dx;
        dx = e.x - xv.x; cl = fmaf(dx, dx, cl);
        dx = e.y - xv.y; cl = fmaf(dx, dx, cl);
        dx = e.z - xv.z; cl = fmaf(dx, dx, cl);
        dx = e.w - xv.w; cl = fmaf(dx, dx, cl);
      }
#pragma unroll
      for (int off = 8; off > 0; off >>= 1) cl += __shfl_down(cl, off, 16);
      if (tid == 0) cl_acc += cl;
    }
    __syncthreads();
  }
  if (tid == 0) atomicAdd(loss_ws, cl_acc);
}

// ---- pass 2 (r3-proven): quantized = tr*(p-hat @ E) + (1-tr)*e_hard ---------
__global__ __launch_bounds__(256, 4) void vq_pass2(
    const float* __restrict__ emb, const unsigned short* __restrict__ p_ws,
    const float* __restrict__ invS_ws, float* __restrict__ out) {
  const int row = blockIdx.x * 256 + threadIdx.x;
  const float invS = invS_ws[row];
  const int imax = (int)out[OUT_IDX + row];
  const uint4* pv = (const uint4*)(p_ws + (size_t)row * 256);
  const float4* e4 = (const float4*)emb;

  float q[32];
#pragma unroll
  for (int d = 0; d < 32; ++d) q[d] = 0.0f;

  for (int kg = 0; kg < 8; ++kg) {
    unsigned int w_[16];
#pragma unroll
    for (int j = 0; j < 4; ++j) {
      const uint4 v = pv[kg * 4 + j];
      w_[4*j+0] = v.x; w_[4*j+1] = v.y; w_[4*j+2] = v.z; w_[4*j+3] = v.w;
    }
#pragma unroll
    for (int i = 0; i < 16; ++i) {
      const int k0 = kg * 32 + 2 * i;
      const float p0 = bf2f(w_[i] & 0xffffu);
      const float p1 = bf2f(w_[i] >> 16);
#pragma unroll
      for (int jj = 0; jj < 8; ++jj) {
        const float4 e0 = e4[k0 * 8 + jj];        // wave-uniform -> s_load
        const float4 e1 = e4[(k0 + 1) * 8 + jj];
        q[4*jj+0] = fmaf(p0, e0.x, fmaf(p1, e1.x, q[4*jj+0]));
        q[4*jj+1] = fmaf(p0, e0.y, fmaf(p1, e1.y, q[4*jj+1]));
        q[4*jj+2] = fmaf(p0, e0.z, fmaf(p1, e1.z, q[4*jj+2]));
        q[4*jj+3] = fmaf(p0, e0.w, fmaf(p1, e1.w, q[4*jj+3]));
      }
    }
  }

  const float tr  = 1.0f / 3.0f;     // (1.0-0.5)/(2.0-0.5)
  const float otr = 1.0f - tr;
  const float4* ehv = (const float4*)(emb + (size_t)imax * 32);
  float4* outq = (float4*)(out + (size_t)row * 32);
#pragma unroll
  for (int j = 0; j < 8; ++j) {
    float4 e = ehv[j];
    float4 o;
    o.x = fmaf(tr, q[4*j+0] * invS, otr * e.x);
    o.y = fmaf(tr, q[4*j+1] * invS, otr * e.y);
    o.z = fmaf(tr, q[4*j+2] * invS, otr * e.z);
    o.w = fmaf(tr, q[4*j+3] * invS, otr * e.w);
    outq[j] = o;
  }
}

// ---- avg_probs column sums (coalesced, 8192 waves) --------------------------
__global__ __launch_bounds__(256) void vq_avg(
    const unsigned short* __restrict__ p_ws, const float* __restrict__ invS_ws,
    float* __restrict__ avg_ws) {
  __shared__ float sh[256];
  const int tid = threadIdx.x, lane = tid & 63, w = tid >> 6;
  sh[tid] = 0.0f;
  __syncthreads();
  const int base = (blockIdx.x * 4 + w) * 32;   // 8192 waves, 32 rows each
  const float iv = invS_ws[base + (lane & 31)];
  float a0 = 0.f, a1 = 0.f, a2 = 0.f, a3 = 0.f;
#pragma unroll 4
  for (int r = 0; r < 32; ++r) {
    const float s = __shfl(iv, r);
    const unsigned short* pr = p_ws + (size_t)(base + r) * 256;
    a0 = fmaf(bf2f(pr[  0 + lane]), s, a0);
    a1 = fmaf(bf2f(pr[ 64 + lane]), s, a1);
    a2 = fmaf(bf2f(pr[128 + lane]), s, a2);
    a3 = fmaf(bf2f(pr[192 + lane]), s, a3);
  }
  atomicAdd(&sh[  0 + lane], a0);
  atomicAdd(&sh[ 64 + lane], a1);
  atomicAdd(&sh[128 + lane], a2);
  atomicAdd(&sh[192 + lane], a3);
  __syncthreads();
  atomicAdd(&avg_ws[tid], sh[tid]);
}

__global__ __launch_bounds__(256) void vq_fin(const float* __restrict__ ws,
                                              float* __restrict__ out) {
  __shared__ float red[256];
  int t = threadIdx.x;
  float avg = ws[t] * (1.0f / 262144.0f);
  red[t] = -avg * __logf(avg + 1e-10f);
  __syncthreads();
  for (int s = 128; s > 0; s >>= 1) {
    if (t < s) red[t] += red[t + s];
    __syncthreads();
  }
  if (t == 0) {
    out[OUT_PPL]  = __expf(red[0]);
    out[OUT_LOSS] = ws[256] * (1.0f / 8388608.0f);
  }
}

// ---- fallback (round-1 monolithic, if ws too small) -------------------------
__global__ __launch_bounds__(256, 1) void vq_main(
    const float* __restrict__ x_in, const float* __restrict__ emb,
    const float* __restrict__ gum, const float* __restrict__ ne,
    float* __restrict__ avg_ws, float* __restrict__ loss_ws,
    float* __restrict__ out) {
  extern __shared__ unsigned char dynsmem[];
  unsigned short* p_lds = (unsigned short*)dynsmem;

  const int tid  = threadIdx.x;
  const int lane = tid & 63;
  const int w    = tid >> 6;
  const int row  = blockIdx.x * 256 + tid;
  unsigned short* my_p = p_lds + (size_t)(w * 64 + lane) * 258;

  float xr[32];
  {
    const float4* xv = (const float4*)(x_in + (size_t)row * 32);
#pragma unroll
    for (int j = 0; j < 8; ++j) {
      float4 v = xv[j];
      xr[4*j+0] = v.x; xr[4*j+1] = v.y; xr[4*j+2] = v.z; xr[4*j+3] = v.w;
    }
  }
  float q[32];
#pragma unroll
  for (int d = 0; d < 32; ++d) q[d] = 0.0f;

  float ssum = 0.0f;
  float tmax = -3.0e38f;
  int   imax = 0;

  const float4* g4 = (const float4*)(gum + (size_t)row * 256);
  const float4* e4 = (const float4*)emb;

  for (int kg = 0; kg < 8; ++kg) {
    float uv[32];
#pragma unroll
    for (int j = 0; j < 8; ++j) {
      float4 v = g4[kg * 8 + j];
      uv[4*j+0] = v.x; uv[4*j+1] = v.y; uv[4*j+2] = v.z; uv[4*j+3] = v.w;
    }
#pragma unroll
    for (int kk = 0; kk < 32; ++kk) {
      const int k = kg * 32 + kk;
      float er[32];
#pragma unroll
      for (int j = 0; j < 8; ++j) {
        float4 v = e4[k * 8 + j];
        er[4*j+0] = v.x; er[4*j+1] = v.y; er[4*j+2] = v.z; er[4*j+3] = v.w;
      }
      float d0 = 0.f, d1 = 0.f, d2 = 0.f, d3 = 0.f;
#pragma unroll
      for (int d = 0; d < 32; d += 4) {
        d0 = fmaf(xr[d+0], er[d+0], d0);
        d1 = fmaf(xr[d+1], er[d+1], d1);
        d2 = fmaf(xr[d+2], er[d+2], d2);
        d3 = fmaf(xr[d+3], er[d+3], d3);
      }
      const float dot = (d0 + d1) + (d2 + d3);
      const float inner = -__logf(uv[kk] + 1e-20f);
      const float g = -__logf(inner + 1e-20f);
      const float t = fmaf(2.0f, dot, g) - ne[k];
      const float p = __expf(t);
      ssum += p;
      if (t > tmax) { tmax = t; imax = k; }
#pragma unroll
      for (int d = 0; d < 32; ++d) q[d] = fmaf(p, er[d], q[d]);
      my_p[k] = (unsigned short)f2bf_u(p);
    }
  }

  const float invS = 1.0f / ssum;
  {
    const float tr  = 1.0f / 3.0f;
    const float otr = 1.0f - tr;
    const float4* ehv = (const float4*)(emb + (size_t)imax * 32);
    float4* outq = (float4*)(out + (size_t)row * 32);
    float cl = 0.0f;
#pragma unroll
    for (int j = 0; j < 8; ++j) {
      float4 e = ehv[j];
      float4 o;
      float qs, dx;
      qs = q[4*j+0]*invS; o.x = tr*qs + otr*e.x; dx = e.x - xr[4*j+0]; cl = fmaf(dx,dx,cl);
      qs = q[4*j+1]*invS; o.y = tr*qs + otr*e.y; dx = e.y - xr[4*j+1]; cl = fmaf(dx,dx,cl);
      qs = q[4*j+2]*invS; o.z = tr*qs + otr*e.z; dx = e.z - xr[4*j+2]; cl = fmaf(dx,dx,cl);
      qs = q[4*j+3]*invS; o.w = tr*qs + otr*e.w; dx = e.w - xr[4*j+3]; cl = fmaf(dx,dx,cl);
      outq[j] = o;
    }
    out[OUT_IDX + row] = (float)imax;
#pragma unroll
    for (int off = 32; off > 0; off >>= 1) cl += __shfl_down(cl, off);
    if (lane == 0) atomicAdd(loss_ws, cl);
  }

  __syncthreads();

  float a0 = 0.f, a1 = 0.f, a2 = 0.f, a3 = 0.f;
  for (int r = 0; r < 64; ++r) {
    const float invS_r = __shfl(invS, r);
    const unsigned short* rp = p_lds + (size_t)(w * 64 + r) * 258;
    a0 = fmaf(bf2f(rp[  0 + lane]), invS_r, a0);
    a1 = fmaf(bf2f(rp[ 64 + lane]), invS_r, a1);
    a2 = fmaf(bf2f(rp[128 + lane]), invS_r, a2);
    a3 = fmaf(bf2f(rp[192 + lane]), invS_r, a3);
  }
  atomicAdd(&avg_ws[  0 + lane], a0);
  atomicAdd(&avg_ws[ 64 + lane], a1);
  atomicAdd(&avg_ws[128 + lane], a2);
  atomicAdd(&avg_ws[192 + lane], a3);
}

extern "C" void kernel_launch(void* const* d_in, const int* in_sizes, int n_in,
                              void* d_out, int out_size, void* d_ws, size_t ws_size,
                              hipStream_t stream) {
  const float* x   = (const float*)d_in[0];
  const float* emb = (const float*)d_in[1];
  const float* gum = (const float*)d_in[2];
  float* out = (float*)d_out;
  float* ws  = (float*)d_ws;

  (void)in_sizes; (void)n_in; (void)out_size;

  vq_prep<<<1, 256, 0, stream>>>(emb, ws);

  const size_t need = (size_t)(1024 + M_ROWS) * 4 + (size_t)M_ROWS * 256 * 2;
  if (ws_size >= need) {
    float* invS = ws + 1024;
    unsigned short* p = (unsigned short*)(ws + 1024 + M_ROWS);
    vq_pass1<<<1024, 256, 0, stream>>>(x, emb, gum, ws + 257, invS, p, ws + 256, out);
    vq_pass2<<<1024, 256, 0, stream>>>(emb, p, invS, out);
    vq_avg<<<2048, 256, 0, stream>>>(p, invS, ws);
  } else {
    hipFuncSetAttribute((const void*)vq_main,
                        hipFuncAttributeMaxDynamicSharedMemorySize, 132128);
    vq_main<<<1024, 256, 132128, stream>>>(x, emb, gum, ws + 257, ws, ws + 256, out);
  }
  vq_fin<<<1, 256, 0, stream>>>(ws, out);
}

// Round 11
// 317.137 us; speedup vs baseline: 7.6084x; 1.0831x over previous
//
#include <hip/hip_runtime.h>

// GumbelVQ — lane=code pass1 (16-row tiles, LDS-staged gumbel) + r3 pass2,
// with packed-f32 FMA (v_pk_fma_f32 via float2 elementwise fma).
// Outputs (concatenated float32 in d_out):
//   [0 .. 8388607]      quantized  [16,16384,32]
//   [8388608]           commitment_loss (scalar)
//   [8388609 .. 8650752] indices   [16,16384] (stored as float)
//   [8650753]           perplexity (scalar)
//
// ws float layout:
//   [0..255]    avg_probs accumulator
//   [256]       loss accumulator
//   [257..512]  ||e_k||^2
//   [1024 .. 1024+M)  invS per row
//   floats from 1024+M : p (unnormalized numerators) bf16 [M][256]
//
// Round-11 change vs round-10 (343us total; pass1 224us, VALUBusy 70%,
// traffic near-ideal -> VALU-ISSUE bound): express the dominant FMA streams
// (pass1 dot, pass2 q-accum) as float2 __builtin_elementwise_fma so LLVM
// emits v_pk_fma_f32 (2 FMA/lane/instr, VOP3P) — halves the dot's issue
// count. Neutral if gfx950 runs pk at half rate (same cycles as 2 v_fma).
// Everything else identical to round-10 (proven structure).

#define M_ROWS  262144
#define OUT_LOSS 8388608
#define OUT_IDX  8388609
#define OUT_PPL  8650753

typedef float f32x2 __attribute__((ext_vector_type(2)));

__device__ __forceinline__ f32x2 mk2(float a, float b) {
  f32x2 r; r.x = a; r.y = b; return r;
}

__device__ __forceinline__ unsigned int f2bf_u(float f) {
  unsigned int u = __float_as_uint(f);
  u += 0x7fffu + ((u >> 16) & 1u);
  return u >> 16;
}
__device__ __forceinline__ float bf2f(unsigned int lo16) {
  return __uint_as_float(lo16 << 16);
}

__global__ __launch_bounds__(256) void vq_prep(const float* __restrict__ emb,
                                               float* __restrict__ ws) {
  int t = threadIdx.x;
  ws[t] = 0.0f;                 // avg accumulators
  if (t == 0) ws[256] = 0.0f;   // loss accumulator
  const float4* e4 = (const float4*)emb;
  float s = 0.0f;
#pragma unroll
  for (int j = 0; j < 8; ++j) {
    float4 v = e4[t * 8 + j];
    s += v.x * v.x + v.y * v.y + v.z * v.z + v.w * v.w;
  }
  ws[257 + t] = s;
}

// ---- pass 1 (lane=code): logits, p(bf16), invS, argmax, loss ----------------
// 1024 blocks x 256 thr; block owns 256 rows in 16 tiles of 16.
__global__ __launch_bounds__(256, 4) void vq_pass1(
    const float* __restrict__ x_in, const float* __restrict__ emb,
    const float* __restrict__ gum, const float* __restrict__ ne,
    float* __restrict__ invS_ws, unsigned short* __restrict__ p_ws,
    float* __restrict__ loss_ws, float* __restrict__ out) {
  __shared__ __align__(16) float x_lds[16 * 36];    // 2304 B (16B-aligned rows)
  __shared__ __align__(16) float g_lds[16 * 256];   // 16384 B gumbel tile
  __shared__ float t_lds[256 * 17];                 // 17408 B [code][row]
  __shared__ float red_sum[16 * 17];                // 1088 B
  __shared__ float red_max[16 * 17];
  __shared__ int   red_idx[16 * 17];

  const int tid = threadIdx.x;

  // embedding row for code=tid, resident in VGPRs (as 16 packed f32x2)
  f32x2 er2[16];
  {
    const float4* e4 = (const float4*)(emb + tid * 32);
#pragma unroll
    for (int j = 0; j < 8; ++j) {
      float4 v = e4[j];
      er2[2*j]   = mk2(v.x, v.y);
      er2[2*j+1] = mk2(v.z, v.w);
    }
  }
  const float ne_t = ne[tid];
  const int row_blk = blockIdx.x * 256;
  float cl_acc = 0.0f;

  for (int tt = 0; tt < 16; ++tt) {
    const int r0 = row_blk + tt * 16;

    // bulk-stage gumbel tile: 4 coalesced float4 loads per thread, all in
    // flight together (one latency, not 16 per thread).
    {
      const float4* gg = (const float4*)gum + (size_t)r0 * 64;
      float4* gd = (float4*)g_lds;
#pragma unroll
      for (int i = 0; i < 4; ++i) gd[i * 256 + tid] = gg[i * 256 + tid];
      if (tid < 128)   // 16 rows of x (one float4 per thread)
        *((float4*)&x_lds[(tid >> 3) * 36 + (tid & 7) * 4]) =
            ((const float4*)x_in)[(size_t)r0 * 8 + tid];
    }
    __syncthreads();

    // ---- phase A: logits for 16 rows x (code = tid), pk-fma dot ----
#pragma unroll 2
    for (int r = 0; r < 16; ++r) {
      const float4* xr4 = (const float4*)&x_lds[r * 36];
      f32x2 a0 = mk2(0.f, 0.f), a1 = mk2(0.f, 0.f);
#pragma unroll
      for (int j = 0; j < 8; ++j) {
        const float4 xv = xr4[j];                   // uniform broadcast read
        a0 = __builtin_elementwise_fma(mk2(xv.x, xv.y), er2[2*j],   a0);
        a1 = __builtin_elementwise_fma(mk2(xv.z, xv.w), er2[2*j+1], a1);
      }
      const float dot = (a0.x + a1.x) + (a0.y + a1.y);
      const float u = g_lds[r * 256 + tid];              // 2 lanes/bank: free
      const float g = -__logf(-__logf(u + 1e-20f) + 1e-20f);
      t_lds[tid * 17 + r] = fmaf(2.0f, dot, g) - ne_t;   // ||x||^2 row-const
    }
    __syncthreads();

    // ---- phase B: row = tid&15, codes (tid>>4)*16 .. +16 ----
    const int lrow = tid & 15;
    const int cs   = tid >> 4;
    {
      float ssum = 0.0f, tmax = -3.0e38f;
      int   kmax = 0;
      unsigned int packs[8];
#pragma unroll
      for (int j = 0; j < 16; ++j) {
        const int k = cs * 16 + j;
        const float tv = t_lds[k * 17 + lrow];   // (16cs+lrow+17j)%32: 2/bank
        const float p = __expf(tv);
        ssum += p;
        if (tv > tmax) { tmax = tv; kmax = k; }
        if (j & 1) packs[j >> 1] |= f2bf_u(p) << 16;   // static index
        else       packs[j >> 1]  = f2bf_u(p);
      }
      uint4* pout = (uint4*)(p_ws + (size_t)(r0 + lrow) * 256 + cs * 16);
      const uint4* pd = (const uint4*)packs;
      pout[0] = pd[0]; pout[1] = pd[1];          // 32B per thread, coalesced
      red_sum[lrow * 17 + cs] = ssum;
      red_max[lrow * 17 + cs] = tmax;
      red_idx[lrow * 17 + cs] = kmax;
    }
    __syncthreads();

    // ---- combine slices, write invS/idx, commitment loss (1 thr/row) ----
    if (tid < 16) {
      float ssum = 0.0f, tmax = -3.0e38f;
      int   kmax = 0;
#pragma unroll
      for (int c = 0; c < 16; ++c) {       // ascending c keeps first-index ties
        ssum += red_sum[tid * 17 + c];
        const float m = red_max[tid * 17 + c];
        if (m > tmax) { tmax = m; kmax = red_idx[tid * 17 + c]; }
      }
      const int rg = r0 + tid;
      invS_ws[rg] = 1.0f / ssum;
      out[OUT_IDX + rg] = (float)kmax;

      const float4* eh = (const float4*)(emb + (size_t)kmax * 32);  // L1-hot
      const float* xrr = &x_lds[tid * 36];
      float cl = 0.0f;
#pragma unroll
      for (int j = 0; j < 8; ++j) {
        const float4 e  = eh[j];
        const float4 xv = ((const float4*)xrr)[j];
        float dx;
        dx = e.x - xv.x; cl = fmaf(dx, dx, cl);
        dx = e.y - xv.y; cl = fmaf(dx, dx, cl);
        dx = e.z - xv.z; cl = fmaf(dx, dx, cl);
        dx = e.w - xv.w; cl = fmaf(dx, dx, cl);
      }
#pragma unroll
      for (int off = 8; off > 0; off >>= 1) cl += __shfl_down(cl, off, 16);
      if (tid == 0) cl_acc += cl;
    }
    __syncthreads();
  }
  if (tid == 0) atomicAdd(loss_ws, cl_acc);
}

// ---- pass 2 (r3-proven structure, pk-fma accum): quantized ------------------
__global__ __launch_bounds__(256, 4) void vq_pass2(
    const float* __restrict__ emb, const unsigned short* __restrict__ p_ws,
    const float* __restrict__ invS_ws, float* __restrict__ out) {
  const int row = blockIdx.x * 256 + threadIdx.x;
  const float invS = invS_ws[row];
  const int imax = (int)out[OUT_IDX + row];
  const uint4* pv = (const uint4*)(p_ws + (size_t)row * 256);
  const float4* e4 = (const float4*)emb;

  f32x2 q2[16];
#pragma unroll
  for (int d = 0; d < 16; ++d) q2[d] = mk2(0.f, 0.f);

  for (int kg = 0; kg < 8; ++kg) {
    unsigned int w_[16];
#pragma unroll
    for (int j = 0; j < 4; ++j) {
      const uint4 v = pv[kg * 4 + j];
      w_[4*j+0] = v.x; w_[4*j+1] = v.y; w_[4*j+2] = v.z; w_[4*j+3] = v.w;
    }
#pragma unroll
    for (int i = 0; i < 16; ++i) {
      const int k0 = kg * 32 + 2 * i;
      const f32x2 pp0 = mk2(bf2f(w_[i] & 0xffffu), bf2f(w_[i] & 0xffffu));
      const f32x2 pp1 = mk2(bf2f(w_[i] >> 16),     bf2f(w_[i] >> 16));
#pragma unroll
      for (int jj = 0; jj < 8; ++jj) {
        const float4 e0 = e4[k0 * 8 + jj];        // wave-uniform -> s_load
        const float4 e1 = e4[(k0 + 1) * 8 + jj];
        q2[2*jj]   = __builtin_elementwise_fma(mk2(e0.x, e0.y), pp0, q2[2*jj]);
        q2[2*jj+1] = __builtin_elementwise_fma(mk2(e0.z, e0.w), pp0, q2[2*jj+1]);
        q2[2*jj]   = __builtin_elementwise_fma(mk2(e1.x, e1.y), pp1, q2[2*jj]);
        q2[2*jj+1] = __builtin_elementwise_fma(mk2(e1.z, e1.w), pp1, q2[2*jj+1]);
      }
    }
  }

  const float tr  = 1.0f / 3.0f;     // (1.0-0.5)/(2.0-0.5)
  const float otr = 1.0f - tr;
  const float4* ehv = (const float4*)(emb + (size_t)imax * 32);
  float4* outq = (float4*)(out + (size_t)row * 32);
#pragma unroll
  for (int j = 0; j < 8; ++j) {
    float4 e = ehv[j];
    float4 o;
    o.x = fmaf(tr, q2[2*j].x   * invS, otr * e.x);
    o.y = fmaf(tr, q2[2*j].y   * invS, otr * e.y);
    o.z = fmaf(tr, q2[2*j+1].x * invS, otr * e.z);
    o.w = fmaf(tr, q2[2*j+1].y * invS, otr * e.w);
    outq[j] = o;
  }
}

// ---- avg_probs column sums (coalesced, 8192 waves) --------------------------
__global__ __launch_bounds__(256) void vq_avg(
    const unsigned short* __restrict__ p_ws, const float* __restrict__ invS_ws,
    float* __restrict__ avg_ws) {
  __shared__ float sh[256];
  const int tid = threadIdx.x, lane = tid & 63, w = tid >> 6;
  sh[tid] = 0.0f;
  __syncthreads();
  const int base = (blockIdx.x * 4 + w) * 32;   // 8192 waves, 32 rows each
  const float iv = invS_ws[base + (lane & 31)];
  float a0 = 0.f, a1 = 0.f, a2 = 0.f, a3 = 0.f;
#pragma unroll 4
  for (int r = 0; r < 32; ++r) {
    const float s = __shfl(iv, r);
    const unsigned short* pr = p_ws + (size_t)(base + r) * 256;
    a0 = fmaf(bf2f(pr[  0 + lane]), s, a0);
    a1 = fmaf(bf2f(pr[ 64 + lane]), s, a1);
    a2 = fmaf(bf2f(pr[128 + lane]), s, a2);
    a3 = fmaf(bf2f(pr[192 + lane]), s, a3);
  }
  atomicAdd(&sh[  0 + lane], a0);
  atomicAdd(&sh[ 64 + lane], a1);
  atomicAdd(&sh[128 + lane], a2);
  atomicAdd(&sh[192 + lane], a3);
  __syncthreads();
  atomicAdd(&avg_ws[tid], sh[tid]);
}

__global__ __launch_bounds__(256) void vq_fin(const float* __restrict__ ws,
                                              float* __restrict__ out) {
  __shared__ float red[256];
  int t = threadIdx.x;
  float avg = ws[t] * (1.0f / 262144.0f);
  red[t] = -avg * __logf(avg + 1e-10f);
  __syncthreads();
  for (int s = 128; s > 0; s >>= 1) {
    if (t < s) red[t] += red[t + s];
    __syncthreads();
  }
  if (t == 0) {
    out[OUT_PPL]  = __expf(red[0]);
    out[OUT_LOSS] = ws[256] * (1.0f / 8388608.0f);
  }
}

// ---- fallback (round-1 monolithic, if ws too small) -------------------------
__global__ __launch_bounds__(256, 1) void vq_main(
    const float* __restrict__ x_in, const float* __restrict__ emb,
    const float* __restrict__ gum, const float* __restrict__ ne,
    float* __restrict__ avg_ws, float* __restrict__ loss_ws,
    float* __restrict__ out) {
  extern __shared__ unsigned char dynsmem[];
  unsigned short* p_lds = (unsigned short*)dynsmem;

  const int tid  = threadIdx.x;
  const int lane = tid & 63;
  const int w    = tid >> 6;
  const int row  = blockIdx.x * 256 + tid;
  unsigned short* my_p = p_lds + (size_t)(w * 64 + lane) * 258;

  float xr[32];
  {
    const float4* xv = (const float4*)(x_in + (size_t)row * 32);
#pragma unroll
    for (int j = 0; j < 8; ++j) {
      float4 v = xv[j];
      xr[4*j+0] = v.x; xr[4*j+1] = v.y; xr[4*j+2] = v.z; xr[4*j+3] = v.w;
    }
  }
  float q[32];
#pragma unroll
  for (int d = 0; d < 32; ++d) q[d] = 0.0f;

  float ssum = 0.0f;
  float tmax = -3.0e38f;
  int   imax = 0;

  const float4* g4 = (const float4*)(gum + (size_t)row * 256);
  const float4* e4 = (const float4*)emb;

  for (int kg = 0; kg < 8; ++kg) {
    float uv[32];
#pragma unroll
    for (int j = 0; j < 8; ++j) {
      float4 v = g4[kg * 8 + j];
      uv[4*j+0] = v.x; uv[4*j+1] = v.y; uv[4*j+2] = v.z; uv[4*j+3] = v.w;
    }
#pragma unroll
    for (int kk = 0; kk < 32; ++kk) {
      const int k = kg * 32 + kk;
      float er[32];
#pragma unroll
      for (int j = 0; j < 8; ++j) {
        float4 v = e4[k * 8 + j];
        er[4*j+0] = v.x; er[4*j+1] = v.y; er[4*j+2] = v.z; er[4*j+3] = v.w;
      }
      float d0 = 0.f, d1 = 0.f, d2 = 0.f, d3 = 0.f;
#pragma unroll
      for (int d = 0; d < 32; d += 4) {
        d0 = fmaf(xr[d+0], er[d+0], d0);
        d1 = fmaf(xr[d+1], er[d+1], d1);
        d2 = fmaf(xr[d+2], er[d+2], d2);
        d3 = fmaf(xr[d+3], er[d+3], d3);
      }
      const float dot = (d0 + d1) + (d2 + d3);
      const float inner = -__logf(uv[kk] + 1e-20f);
      const float g = -__logf(inner + 1e-20f);
      const float t = fmaf(2.0f, dot, g) - ne[k];
      const float p = __expf(t);
      ssum += p;
      if (t > tmax) { tmax = t; imax = k; }
#pragma unroll
      for (int d = 0; d < 32; ++d) q[d] = fmaf(p, er[d], q[d]);
      my_p[k] = (unsigned short)f2bf_u(p);
    }
  }

  const float invS = 1.0f / ssum;
  {
    const float tr  = 1.0f / 3.0f;
    const float otr = 1.0f - tr;
    const float4* ehv = (const float4*)(emb + (size_t)imax * 32);
    float4* outq = (float4*)(out + (size_t)row * 32);
    float cl = 0.0f;
#pragma unroll
    for (int j = 0; j < 8; ++j) {
      float4 e = ehv[j];
      float4 o;
      float qs, dx;
      qs = q[4*j+0]*invS; o.x = tr*qs + otr*e.x; dx = e.x - xr[4*j+0]; cl = fmaf(dx,dx,cl);
      qs = q[4*j+1]*invS; o.y = tr*qs + otr*e.y; dx = e.y - xr[4*j+1]; cl = fmaf(dx,dx,cl);
      qs = q[4*j+2]*invS; o.z = tr*qs + otr*e.z; dx = e.z - xr[4*j+2]; cl = fmaf(dx,dx,cl);
      qs = q[4*j+3]*invS; o.w = tr*qs + otr*e.w; dx = e.w - xr[4*j+3]; cl = fmaf(dx,dx,cl);
      outq[j] = o;
    }
    out[OUT_IDX + row] = (float)imax;
#pragma unroll
    for (int off = 32; off > 0; off >>= 1) cl += __shfl_down(cl, off);
    if (lane == 0) atomicAdd(loss_ws, cl);
  }

  __syncthreads();

  float a0 = 0.f, a1 = 0.f, a2 = 0.f, a3 = 0.f;
  for (int r = 0; r < 64; ++r) {
    const float invS_r = __shfl(invS, r);
    const unsigned short* rp = p_lds + (size_t)(w * 64 + r) * 258;
    a0 = fmaf(bf2f(rp[  0 + lane]), invS_r, a0);
    a1 = fmaf(bf2f(rp[ 64 + lane]), invS_r, a1);
    a2 = fmaf(bf2f(rp[128 + lane]), invS_r, a2);
    a3 = fmaf(bf2f(rp[192 + lane]), invS_r, a3);
  }
  atomicAdd(&avg_ws[  0 + lane], a0);
  atomicAdd(&avg_ws[ 64 + lane], a1);
  atomicAdd(&avg_ws[128 + lane], a2);
  atomicAdd(&avg_ws[192 + lane], a3);
}

extern "C" void kernel_launch(void* const* d_in, const int* in_sizes, int n_in,
                              void* d_out, int out_size, void* d_ws, size_t ws_size,
                              hipStream_t stream) {
  const float* x   = (const float*)d_in[0];
  const float* emb = (const float*)d_in[1];
  const float* gum = (const float*)d_in[2];
  float* out = (float*)d_out;
  float* ws  = (float*)d_ws;

  (void)in_sizes; (void)n_in; (void)out_size;

  vq_prep<<<1, 256, 0, stream>>>(emb, ws);

  const size_t need = (size_t)(1024 + M_ROWS) * 4 + (size_t)M_ROWS * 256 * 2;
  if (ws_size >= need) {
    float* invS = ws + 1024;
    unsigned short* p = (unsigned short*)(ws + 1024 + M_ROWS);
    vq_pass1<<<1024, 256, 0, stream>>>(x, emb, gum, ws + 257, invS, p, ws + 256, out);
    vq_pass2<<<1024, 256, 0, stream>>>(emb, p, invS, out);
    vq_avg<<<2048, 256, 0, stream>>>(p, invS, ws);
  } else {
    hipFuncSetAttribute((const void*)vq_main,
                        hipFuncAttributeMaxDynamicSharedMemorySize, 132128);
    vq_main<<<1024, 256, 132128, stream>>>(x, emb, gum, ws + 257, ws, ws + 256, out);
  }
  vq_fin<<<1, 256, 0, stream>>>(ws, out);
}